// Round 21
// baseline (539.292 us; speedup 1.0000x reference)
//
#include <hip/hip_runtime.h>
#include <hip/hip_bf16.h>
#include <math.h>

#define NDIM 384
#define NHEADS 12
#define NTOK 196
#define NBATCH 256
#define M_TOK (NBATCH * NTOK)   // 50176
#define NHID 1536
#define THREE_DIM 1152
#define HD 32
#define EPSV 1e-5f
#define BH_STRIDE 7168          // 224*32 elements per (b,h) padded slice
#define BPAD 224                // padded token count
#define LOG2E 1.4426950408889634f

typedef __hip_bfloat16 bf16;
typedef __attribute__((ext_vector_type(8))) short short8;
typedef __attribute__((ext_vector_type(4))) short short4v;
typedef __attribute__((ext_vector_type(4))) float f32x4;

__device__ __forceinline__ void gload_lds16(const void* g, void* l) {
  __builtin_amdgcn_global_load_lds((const __attribute__((address_space(1))) void*)g,
                                   (__attribute__((address_space(3))) void*)l, 16, 0, 0);
}

// ---------------- prep: weight transpose fp32 -> bf16 (dst[n*K+k] = src[k*N+n])
__global__ void k_transpose_bf16(const float* __restrict__ src, bf16* __restrict__ dst,
                                 int K, int N) {
  int idx = blockIdx.x * 256 + threadIdx.x;
  if (idx >= K * N) return;
  int k = idx / N, n = idx - k * N;
  dst[n * K + k] = __float2bfloat16(src[idx]);
}

// ---------------- prep: bias in SWAPPED-QK^T MFMA C-operand layout (x log2e).
// s = mfma(K_frag, Q_frag, bias_c): D row = key, D col = q.
// bias_c[(((h*13+qt)*13+kt)*64+lane)] : f32x4, elem e = bias at
// (key = kt*16 + (lane>>4)*4 + e  [pad -> -1e30], q = qt*16 + (lane&15) [clamped]).
__global__ void k_build_biasc(const float* __restrict__ table, const int* __restrict__ rpi,
                              f32x4* __restrict__ bias_c) {
  int idx = blockIdx.x * 256 + threadIdx.x;
  if (idx >= NHEADS * 13 * 13 * 64) return;
  int lane = idx & 63;
  int tmp = idx >> 6;
  int kt = tmp % 13; tmp /= 13;
  int qt = tmp % 13;
  int h = tmp / 13;
  int lo = lane & 15, hi = lane >> 4;
  int qg = qt * 16 + lo;
  int qc = qg < NTOK ? qg : NTOK - 1;
  f32x4 v;
#pragma unroll
  for (int e = 0; e < 4; ++e) {
    int key = kt * 16 + hi * 4 + e;
    v[e] = (key >= NTOK) ? -1e30f
                         : table[rpi[qc * NTOK + key] * NHEADS + h] * LOG2E;
  }
  bias_c[idx] = v;
}

// ---------------- LayerNorm: 1 wave per token, 4 tokens per block
__global__ __launch_bounds__(256) void k_layernorm(const float* __restrict__ x,
                                                   const float* __restrict__ w,
                                                   const float* __restrict__ b,
                                                   bf16* __restrict__ out) {
  int token = blockIdx.x * 4 + (threadIdx.x >> 6);
  int lane = threadIdx.x & 63;
  const float* xr = x + (size_t)token * NDIM;
  float v[6];
  float s = 0.f;
#pragma unroll
  for (int i = 0; i < 6; ++i) { v[i] = xr[lane + i * 64]; s += v[i]; }
#pragma unroll
  for (int off = 32; off >= 1; off >>= 1) s += __shfl_xor(s, off);
  float mu = s * (1.f / NDIM);
  float s2 = 0.f;
#pragma unroll
  for (int i = 0; i < 6; ++i) { float d = v[i] - mu; s2 += d * d; }
#pragma unroll
  for (int off = 32; off >= 1; off >>= 1) s2 += __shfl_xor(s2, off);
  float r = rsqrtf(s2 * (1.f / NDIM) + EPSV);
  bf16* orow = out + (size_t)token * NDIM;
#pragma unroll
  for (int i = 0; i < 6; ++i) {
    int c = lane + i * 64;
    orow[c] = __float2bfloat16((v[i] - mu) * r * w[c] + b[c]);
  }
}

// ---------------- shared epilogue (swapped-operand layout)
template <int EPI>
__device__ __forceinline__ void gemm_epilogue(const f32x4 acc[4][4], int m0, int n0,
                                              int lo, int hi,
                                              const float* __restrict__ bias,
                                              const float* __restrict__ resid,
                                              void* __restrict__ Cout,
                                              bf16* __restrict__ pq,
                                              bf16* __restrict__ pk,
                                              bf16* __restrict__ pv, int Nn) {
  const float qscale = 0.17677669529663687f * LOG2E;  // exp2-folded
#pragma unroll
  for (int i = 0; i < 4; ++i) {
    int r = m0 + i * 16 + lo;
#pragma unroll
    for (int j = 0; j < 4; ++j) {
      int cb0 = n0 + j * 16 + hi * 4;
      f32x4 bv = *(const f32x4*)(bias + cb0);
      f32x4 v;
#pragma unroll
      for (int e = 0; e < 4; ++e) v[e] = acc[i][j][e] + bv[e];
      if (EPI == 3) {
        int d0 = cb0 & 31;
        int hseg = cb0 >> 5;
        int which = hseg / 12;
        int h = hseg - which * 12;
        int b = r / 196;
        int t = r - b * 196;
        size_t base = (size_t)(b * 12 + h) * BH_STRIDE;
        if (which == 2) {
#pragma unroll
          for (int e = 0; e < 4; ++e)
            pv[base + (d0 + e) * BPAD + t] = __float2bfloat16(v[e]);
        } else if (which == 1) {
          union { short4v s; bf16 x[4]; } pack;
#pragma unroll
          for (int e = 0; e < 4; ++e) pack.x[e] = __float2bfloat16(v[e]);
          *(short4v*)(pk + base + t * 32 + d0) = pack.s;
        } else {
          union { short4v s; bf16 x[4]; } pack;
#pragma unroll
          for (int e = 0; e < 4; ++e) pack.x[e] = __float2bfloat16(v[e] * qscale);
          *(short4v*)(pq + base + t * 32 + d0) = pack.s;
        }
      } else if (EPI == 2) {
        size_t idx = (size_t)r * Nn + cb0;
        f32x4 rs = *(const f32x4*)(resid + idx);
#pragma unroll
        for (int e = 0; e < 4; ++e) v[e] += rs[e];
        *(f32x4*)((float*)Cout + idx) = v;
      } else {
        if (EPI == 1) {
#pragma unroll
          for (int e = 0; e < 4; ++e) {
            float val = v[e];
            float t = val * val;
            float p = __builtin_fmaf(0.044715f * val, t, val);
            float E = __expf(1.5957691216057308f * p);
            float rr = __builtin_amdgcn_rcpf(E + 1.f);
            v[e] = val - val * rr;
          }
        }
        union { short4v s; bf16 x[4]; } pack;
#pragma unroll
        for (int e = 0; e < 4; ++e) pack.x[e] = __float2bfloat16(v[e]);
        size_t idx = (size_t)r * Nn + cb0;
        *(short4v*)((bf16*)Cout + idx) = pack.s;
      }
    }
  }
}

// ---------------- GEMM: C[M,N] = A[M,K] * Bt[N,K]^T + bias
// 256x128 tile, 8 waves, BK=64: 256 MFMA per barrier (2 sub-steps of 128),
// same proven 2-buffer one-__syncthreads-per-K-tile pipeline. 96KB LDS is
// free: measured residency is already 1 block/CU at 48KB (R20 occupancy 26%).
// T2 LDS swizzle + bijective XCD-chunked block swizzle (m204).
template <int EPI>
__global__ __launch_bounds__(512) void k_gemm_bt(const bf16* __restrict__ A,
                                                 const bf16* __restrict__ Bt,
                                                 const float* __restrict__ bias,
                                                 const float* __restrict__ resid,
                                                 void* __restrict__ Cout,
                                                 bf16* __restrict__ pq,
                                                 bf16* __restrict__ pk,
                                                 bf16* __restrict__ pv,
                                                 int Nn, int K, int nbx) {
  // per buffer: A = two 256x32 panels (8192 elems each), B = two 128x32 panels
  __shared__ __align__(16) bf16 As[2][2 * 8192];   // 32KB x2
  __shared__ __align__(16) bf16 Bs[2][2 * 4096];   // 16KB x2
  const int tid = threadIdx.x;
  const int wave = tid >> 6, lane = tid & 63;
  const int lo = lane & 15, hi = lane >> 4;
  const int wm = wave >> 1, wn = wave & 1;

  const int nwg = gridDim.x;
  const int xcd = blockIdx.x & 7, bidx = blockIdx.x >> 3;
  const int q = nwg >> 3, rr8 = nwg & 7;
  const int swz = (xcd < rr8 ? xcd * (q + 1) : rr8 * (q + 1) + (xcd - rr8) * q) + bidx;
  const int m0 = (swz / nbx) * 256, n0 = (swz % nbx) * 128;

  f32x4 acc[4][4];
#pragma unroll
  for (int i = 0; i < 4; ++i)
#pragma unroll
    for (int j = 0; j < 4; ++j) acc[i][j] = (f32x4){0.f, 0.f, 0.f, 0.f};

  const int rowA0 = tid >> 2, part = tid & 3;
  const int sw = part ^ ((rowA0 >> 1) & 3);
  const bf16* ArowP0 = A + (size_t)(m0 + rowA0) * K + sw * 8;
  const bf16* ArowP1 = A + (size_t)(m0 + 128 + rowA0) * K + sw * 8;
  const bf16* BrowP = Bt + (size_t)(n0 + rowA0) * K + sw * 8;

  // stage one BK=64 tile = two 32-wide panels, each with the proven layout
#define STAGE(kt, abuf, bbuf)                                        \
  {                                                                  \
    int k0_ = (kt) << 6;                                             \
    gload_lds16(ArowP0 + k0_, (abuf) + tid * 8);                     \
    gload_lds16(ArowP1 + k0_, (abuf) + (512 + tid) * 8);             \
    gload_lds16(BrowP + k0_, (bbuf) + tid * 8);                      \
    gload_lds16(ArowP0 + k0_ + 32, (abuf) + 8192 + tid * 8);         \
    gload_lds16(ArowP1 + k0_ + 32, (abuf) + 8192 + (512 + tid) * 8); \
    gload_lds16(BrowP + k0_ + 32, (bbuf) + 4096 + tid * 8);          \
  }

  const int nt = K >> 6;
  STAGE(0, As[0], Bs[0]);
  __syncthreads();

  const int rsw = (lo >> 1) & 3;
  int cur = 0;
  for (int t = 0; t < nt; ++t) {
    if (t + 1 < nt) STAGE(t + 1, As[cur ^ 1], Bs[cur ^ 1]);
#pragma unroll
    for (int p = 0; p < 2; ++p) {
      short8 af[4], bfr[4];
#pragma unroll
      for (int i = 0; i < 4; ++i) {
        af[i] = *(const short8*)(As[cur] + p * 8192 +
                                 (wm * 64 + i * 16 + lo) * 32 + (hi ^ rsw) * 8);
        bfr[i] = *(const short8*)(Bs[cur] + p * 4096 +
                                  (wn * 64 + i * 16 + lo) * 32 + (hi ^ rsw) * 8);
      }
#pragma unroll
      for (int i = 0; i < 4; ++i)
#pragma unroll
        for (int j = 0; j < 4; ++j)
          acc[i][j] = __builtin_amdgcn_mfma_f32_16x16x32_bf16(bfr[j], af[i], acc[i][j], 0, 0, 0);
    }
    __syncthreads();
    cur ^= 1;
  }
#undef STAGE

  gemm_epilogue<EPI>(acc, m0 + wm * 64, n0 + wn * 64, lo, hi, bias, resid, Cout,
                     pq, pk, pv, Nn);
}

// ---------------- attention: 1 wave per (b,h,qt); SWAPPED QK^T.
// s[kt] = mfma(K,Q,bias_c): lane holds P[key=kt*16+hi*4+e][q=lo].
// Softmax: per-lane partial sum + 2 shfl_xor(16,32) full-row reduce; one rcp.
// P relayout: 13 packed ds_write_b64 (4 consecutive keys per lane per kt).
__global__ __launch_bounds__(256) void k_attn(const bf16* __restrict__ Qp,
                                              const bf16* __restrict__ Kp,
                                              const bf16* __restrict__ Vtp,
                                              const f32x4* __restrict__ bias_c,
                                              bf16* __restrict__ out) {
  __shared__ __align__(16) bf16 Ps[4][16][232];
  const int tid = threadIdx.x;
  const int wave = tid >> 6, lane = tid & 63;
  const int lo = lane & 15, hi = lane >> 4;
  const int nwg = gridDim.x;
  const int swz = (blockIdx.x & 7) * (nwg >> 3) + (blockIdx.x >> 3);
  const int unit = swz * 4 + wave;          // 0..39935
  const int bh = unit / 13;
  const int qt = unit - bh * 13;
  const int h = bh % 12;
  const int b = bh / 12;
  const bf16* Qb = Qp + (size_t)bh * BH_STRIDE;
  const bf16* Kb = Kp + (size_t)bh * BH_STRIDE;
  const bf16* Vb = Vtp + (size_t)bh * BH_STRIDE;
  const f32x4* bc = bias_c + ((size_t)(h * 13 + qt) * 13) * 64 + lane;

  // zero this wave's P pad cols 208..223
  for (int i = lane; i < 256; i += 64)
    Ps[wave][i >> 4][208 + (i & 15)] = __float2bfloat16(0.f);

  short8 qf = *(const short8*)(Qb + (qt * 16 + lo) * 32 + hi * 8);

  f32x4 s[13];
  __builtin_amdgcn_s_setprio(1);
#pragma unroll
  for (int kt = 0; kt < 13; ++kt) {
    short8 kf = *(const short8*)(Kb + (kt * 16 + lo) * 32 + hi * 8);
    s[kt] = __builtin_amdgcn_mfma_f32_16x16x32_bf16(kf, qf, bc[kt * 64], 0, 0, 0);
  }
  __builtin_amdgcn_s_setprio(0);

  // p = 2^s; per-lane partial row-sum (q = lo), then reduce over hi groups
  float sm = 0.f;
#pragma unroll
  for (int kt = 0; kt < 13; ++kt) {
#pragma unroll
    for (int e = 0; e < 4; ++e) {
      float pe = __builtin_amdgcn_exp2f(s[kt][e]);
      s[kt][e] = pe;
      sm += pe;
    }
  }
  sm += __shfl_xor(sm, 16);
  sm += __shfl_xor(sm, 32);
  float invq = 1.f / sm;   // 1/rowsum for q = lo

  // P -> LDS: packed 4-key writes, row = q = lo
#pragma unroll
  for (int kt = 0; kt < 13; ++kt) {
    union { short4v v; bf16 x[4]; } pack;
#pragma unroll
    for (int e = 0; e < 4; ++e) pack.x[e] = __float2bfloat16(s[kt][e]);
    *(short4v*)(&Ps[wave][lo][kt * 16 + hi * 4]) = pack.v;
  }

  // O = P V (unnormalized P)
  f32x4 o[2] = {{0.f, 0.f, 0.f, 0.f}, {0.f, 0.f, 0.f, 0.f}};
  __builtin_amdgcn_s_setprio(1);
#pragma unroll
  for (int c = 0; c < 7; ++c) {
    short8 pa = *(const short8*)(&Ps[wave][lo][c * 32 + hi * 8]);
#pragma unroll
    for (int n = 0; n < 2; ++n) {
      short8 vf = *(const short8*)(Vb + (n * 16 + lo) * BPAD + c * 32 + hi * 8);
      o[n] = __builtin_amdgcn_mfma_f32_16x16x32_bf16(pa, vf, o[n], 0, 0, 0);
    }
  }
  __builtin_amdgcn_s_setprio(0);

  // output row hi*4+e needs inv of q-row hi*4+e (lives in lane lo = hi*4+e)
  f32x4 inv;
#pragma unroll
  for (int e = 0; e < 4; ++e) inv[e] = __shfl(invq, hi * 4 + e);

#pragma unroll
  for (int n = 0; n < 2; ++n) {
#pragma unroll
    for (int e = 0; e < 4; ++e) {
      int qg = qt * 16 + hi * 4 + e;
      if (qg < NTOK)
        out[(size_t)(b * NTOK + qg) * NDIM + h * HD + n * 16 + lo] =
            __float2bfloat16(o[n][e] * inv[e]);
    }
  }
}

extern "C" void kernel_launch(void* const* d_in, const int* in_sizes, int n_in,
                              void* d_out, int out_size, void* d_ws, size_t ws_size,
                              hipStream_t stream) {
  const float* x       = (const float*)d_in[0];
  const float* norm1_w = (const float*)d_in[1];
  const float* norm1_b = (const float*)d_in[2];
  const float* qkv_w   = (const float*)d_in[3];
  const float* qkv_b   = (const float*)d_in[4];
  const float* proj_w  = (const float*)d_in[5];
  const float* proj_b  = (const float*)d_in[6];
  const float* rpb     = (const float*)d_in[7];
  const float* norm2_w = (const float*)d_in[8];
  const float* norm2_b = (const float*)d_in[9];
  const float* fc1_w   = (const float*)d_in[10];
  const float* fc1_b   = (const float*)d_in[11];
  const float* fc2_w   = (const float*)d_in[12];
  const float* fc2_b   = (const float*)d_in[13];
  const int*   rpi     = (const int*)d_in[14];
  float* out = (float*)d_out;

  char* ws = (char*)d_ws;
  bf16* pad_q = (bf16*)ws;
  bf16* pad_k = (bf16*)(ws + 44040192);
  bf16* pad_v = (bf16*)(ws + 2 * 44040192);
  f32x4* bias_c = (f32x4*)(ws + 3 * 44040192);  // 12*13*13*64*16B = 2,076,672 B
  bf16* mlp1 = (bf16*)ws;
  bf16* hbuf = (bf16*)(ws + 154140672);
  bf16* wqkv_t = (bf16*)(ws + 154140672 + 38535168);
  bf16* wproj_t = wqkv_t + 442368;
  bf16* wfc1_t = wproj_t + 147456;
  bf16* wfc2_t = wfc1_t + 589824;

  k_transpose_bf16<<<(442368 + 255) / 256, 256, 0, stream>>>(qkv_w, wqkv_t, 384, 1152);
  k_transpose_bf16<<<(147456 + 255) / 256, 256, 0, stream>>>(proj_w, wproj_t, 384, 384);
  k_transpose_bf16<<<(589824 + 255) / 256, 256, 0, stream>>>(fc1_w, wfc1_t, 384, 1536);
  k_transpose_bf16<<<(589824 + 255) / 256, 256, 0, stream>>>(fc2_w, wfc2_t, 1536, 384);
  k_build_biasc<<<(NHEADS * 13 * 13 * 64 + 255) / 256, 256, 0, stream>>>(rpb, rpi, bias_c);

  // h1 = LN1(x)
  k_layernorm<<<M_TOK / 4, 256, 0, stream>>>(x, norm1_w, norm1_b, hbuf);
  // qkv = h1 @ qkv_w + qkv_b, scattered into padded per-head buffers
  k_gemm_bt<3><<<196 * 9, 512, 0, stream>>>(hbuf, wqkv_t, qkv_b, nullptr, nullptr,
                                            pad_q, pad_k, pad_v, 1152, 384, 9);
  // attn_out = softmax(q k^T * scale + bias) v
  k_attn<<<9984, 256, 0, stream>>>(pad_q, pad_k, pad_v, bias_c, hbuf);
  // x2 = x + attn_out @ proj_w + proj_b
  k_gemm_bt<2><<<196 * 3, 512, 0, stream>>>(hbuf, wproj_t, proj_b, x, out,
                                            nullptr, nullptr, nullptr, 384, 384, 3);
  // h2 = LN2(x2)
  k_layernorm<<<M_TOK / 4, 256, 0, stream>>>(out, norm2_w, norm2_b, hbuf);
  // mlp1 = gelu(h2 @ fc1_w + fc1_b)
  k_gemm_bt<1><<<196 * 12, 512, 0, stream>>>(hbuf, wfc1_t, fc1_b, nullptr, mlp1,
                                             nullptr, nullptr, nullptr, 1536, 384, 12);
  // out = x2 + mlp1 @ fc2_w + fc2_b
  k_gemm_bt<2><<<196 * 3, 512, 0, stream>>>(mlp1, wfc2_t, fc2_b, out, out,
                                            nullptr, nullptr, nullptr, 384, 1536, 3);
}

// Round 22
// 492.614 us; speedup vs baseline: 1.0948x; 1.0948x over previous
//
#include <hip/hip_runtime.h>
#include <hip/hip_bf16.h>
#include <math.h>

#define NDIM 384
#define NHEADS 12
#define NTOK 196
#define NBATCH 256
#define M_TOK (NBATCH * NTOK)   // 50176
#define NHID 1536
#define THREE_DIM 1152
#define HD 32
#define EPSV 1e-5f
#define BH_STRIDE 7168          // 224*32 elements per (b,h) padded slice
#define BPAD 224                // padded token count
#define LOG2E 1.4426950408889634f

typedef __hip_bfloat16 bf16;
typedef __attribute__((ext_vector_type(8))) short short8;
typedef __attribute__((ext_vector_type(4))) short short4v;
typedef __attribute__((ext_vector_type(4))) float f32x4;

__device__ __forceinline__ void gload_lds16(const void* g, void* l) {
  __builtin_amdgcn_global_load_lds((const __attribute__((address_space(1))) void*)g,
                                   (__attribute__((address_space(3))) void*)l, 16, 0, 0);
}

// ---------------- prep: weight transpose fp32 -> bf16 (dst[n*K+k] = src[k*N+n])
__global__ void k_transpose_bf16(const float* __restrict__ src, bf16* __restrict__ dst,
                                 int K, int N) {
  int idx = blockIdx.x * 256 + threadIdx.x;
  if (idx >= K * N) return;
  int k = idx / N, n = idx - k * N;
  dst[n * K + k] = __float2bfloat16(src[idx]);
}

// ---------------- prep: bias in SWAPPED-QK^T MFMA C-operand layout (x log2e).
// s = mfma(K_frag, Q_frag, bias_c): D row = key, D col = q.
// bias_c[(((h*13+qt)*13+kt)*64+lane)] : f32x4, elem e = bias at
// (key = kt*16 + (lane>>4)*4 + e  [pad -> -1e30], q = qt*16 + (lane&15) [clamped]).
__global__ void k_build_biasc(const float* __restrict__ table, const int* __restrict__ rpi,
                              f32x4* __restrict__ bias_c) {
  int idx = blockIdx.x * 256 + threadIdx.x;
  if (idx >= NHEADS * 13 * 13 * 64) return;
  int lane = idx & 63;
  int tmp = idx >> 6;
  int kt = tmp % 13; tmp /= 13;
  int qt = tmp % 13;
  int h = tmp / 13;
  int lo = lane & 15, hi = lane >> 4;
  int qg = qt * 16 + lo;
  int qc = qg < NTOK ? qg : NTOK - 1;
  f32x4 v;
#pragma unroll
  for (int e = 0; e < 4; ++e) {
    int key = kt * 16 + hi * 4 + e;
    v[e] = (key >= NTOK) ? -1e30f
                         : table[rpi[qc * NTOK + key] * NHEADS + h] * LOG2E;
  }
  bias_c[idx] = v;
}

// ---------------- LayerNorm: 1 wave per token, 4 tokens per block
__global__ __launch_bounds__(256) void k_layernorm(const float* __restrict__ x,
                                                   const float* __restrict__ w,
                                                   const float* __restrict__ b,
                                                   bf16* __restrict__ out) {
  int token = blockIdx.x * 4 + (threadIdx.x >> 6);
  int lane = threadIdx.x & 63;
  const float* xr = x + (size_t)token * NDIM;
  float v[6];
  float s = 0.f;
#pragma unroll
  for (int i = 0; i < 6; ++i) { v[i] = xr[lane + i * 64]; s += v[i]; }
#pragma unroll
  for (int off = 32; off >= 1; off >>= 1) s += __shfl_xor(s, off);
  float mu = s * (1.f / NDIM);
  float s2 = 0.f;
#pragma unroll
  for (int i = 0; i < 6; ++i) { float d = v[i] - mu; s2 += d * d; }
#pragma unroll
  for (int off = 32; off >= 1; off >>= 1) s2 += __shfl_xor(s2, off);
  float r = rsqrtf(s2 * (1.f / NDIM) + EPSV);
  bf16* orow = out + (size_t)token * NDIM;
#pragma unroll
  for (int i = 0; i < 6; ++i) {
    int c = lane + i * 64;
    orow[c] = __float2bfloat16((v[i] - mu) * r * w[c] + b[c]);
  }
}

// ---------------- shared epilogue (swapped-operand layout)
template <int EPI>
__device__ __forceinline__ void gemm_epilogue(const f32x4 acc[4][4], int m0, int n0,
                                              int lo, int hi,
                                              const float* __restrict__ bias,
                                              const float* __restrict__ resid,
                                              void* __restrict__ Cout,
                                              bf16* __restrict__ pq,
                                              bf16* __restrict__ pk,
                                              bf16* __restrict__ pv, int Nn) {
  const float qscale = 0.17677669529663687f * LOG2E;  // exp2-folded
#pragma unroll
  for (int i = 0; i < 4; ++i) {
    int r = m0 + i * 16 + lo;
#pragma unroll
    for (int j = 0; j < 4; ++j) {
      int cb0 = n0 + j * 16 + hi * 4;
      f32x4 bv = *(const f32x4*)(bias + cb0);
      f32x4 v;
#pragma unroll
      for (int e = 0; e < 4; ++e) v[e] = acc[i][j][e] + bv[e];
      if (EPI == 3) {
        int d0 = cb0 & 31;
        int hseg = cb0 >> 5;
        int which = hseg / 12;
        int h = hseg - which * 12;
        int b = r / 196;
        int t = r - b * 196;
        size_t base = (size_t)(b * 12 + h) * BH_STRIDE;
        if (which == 2) {
#pragma unroll
          for (int e = 0; e < 4; ++e)
            pv[base + (d0 + e) * BPAD + t] = __float2bfloat16(v[e]);
        } else if (which == 1) {
          union { short4v s; bf16 x[4]; } pack;
#pragma unroll
          for (int e = 0; e < 4; ++e) pack.x[e] = __float2bfloat16(v[e]);
          *(short4v*)(pk + base + t * 32 + d0) = pack.s;
        } else {
          union { short4v s; bf16 x[4]; } pack;
#pragma unroll
          for (int e = 0; e < 4; ++e) pack.x[e] = __float2bfloat16(v[e] * qscale);
          *(short4v*)(pq + base + t * 32 + d0) = pack.s;
        }
      } else if (EPI == 2) {
        size_t idx = (size_t)r * Nn + cb0;
        f32x4 rs = *(const f32x4*)(resid + idx);
#pragma unroll
        for (int e = 0; e < 4; ++e) v[e] += rs[e];
        *(f32x4*)((float*)Cout + idx) = v;
      } else {
        if (EPI == 1) {
#pragma unroll
          for (int e = 0; e < 4; ++e) {
            float val = v[e];
            float t = val * val;
            float p = __builtin_fmaf(0.044715f * val, t, val);
            float E = __expf(1.5957691216057308f * p);
            float rr = __builtin_amdgcn_rcpf(E + 1.f);
            v[e] = val - val * rr;
          }
        }
        union { short4v s; bf16 x[4]; } pack;
#pragma unroll
        for (int e = 0; e < 4; ++e) pack.x[e] = __float2bfloat16(v[e]);
        size_t idx = (size_t)r * Nn + cb0;
        *(short4v*)((bf16*)Cout + idx) = pack.s;
      }
    }
  }
}

// ---------------- GEMM: C[M,N] = A[M,K] * Bt[N,K]^T + bias
// 256x128 tile, 8 waves: 128 MFMA per barrier, 2-buffer pipeline, T2 LDS
// swizzle, bijective XCD swizzle. PROVEN OPTIMUM of this session — six
// structural variants (R6/R11/R15/R18/R21 + direct) all regressed. Frozen.
template <int EPI>
__global__ __launch_bounds__(512) void k_gemm_bt(const bf16* __restrict__ A,
                                                 const bf16* __restrict__ Bt,
                                                 const float* __restrict__ bias,
                                                 const float* __restrict__ resid,
                                                 void* __restrict__ Cout,
                                                 bf16* __restrict__ pq,
                                                 bf16* __restrict__ pk,
                                                 bf16* __restrict__ pv,
                                                 int Nn, int K, int nbx) {
  __shared__ __align__(16) bf16 As[2][8192];   // 256 x 32
  __shared__ __align__(16) bf16 Bs[2][4096];   // 128 x 32
  const int tid = threadIdx.x;
  const int wave = tid >> 6, lane = tid & 63;
  const int lo = lane & 15, hi = lane >> 4;
  const int wm = wave >> 1, wn = wave & 1;

  const int nwg = gridDim.x;
  const int xcd = blockIdx.x & 7, bidx = blockIdx.x >> 3;
  const int q = nwg >> 3, rr8 = nwg & 7;
  const int swz = (xcd < rr8 ? xcd * (q + 1) : rr8 * (q + 1) + (xcd - rr8) * q) + bidx;
  const int m0 = (swz / nbx) * 256, n0 = (swz % nbx) * 128;

  f32x4 acc[4][4];
#pragma unroll
  for (int i = 0; i < 4; ++i)
#pragma unroll
    for (int j = 0; j < 4; ++j) acc[i][j] = (f32x4){0.f, 0.f, 0.f, 0.f};

  const int rowA0 = tid >> 2, part = tid & 3;
  const int sw = part ^ ((rowA0 >> 1) & 3);
  const bf16* ArowP0 = A + (size_t)(m0 + rowA0) * K + sw * 8;
  const bf16* ArowP1 = A + (size_t)(m0 + 128 + rowA0) * K + sw * 8;
  const bf16* BrowP = Bt + (size_t)(n0 + rowA0) * K + sw * 8;

#define STAGE(ks, abuf, bbuf)                                   \
  {                                                             \
    int k0_ = (ks) << 5;                                        \
    gload_lds16(ArowP0 + k0_, (abuf) + tid * 8);                \
    gload_lds16(ArowP1 + k0_, (abuf) + (512 + tid) * 8);        \
    gload_lds16(BrowP + k0_, (bbuf) + tid * 8);                 \
  }

  const int nk = K >> 5;
  STAGE(0, As[0], Bs[0]);
  __syncthreads();

  const int rsw = (lo >> 1) & 3;
  int cur = 0;
  for (int ks = 0; ks < nk; ++ks) {
    if (ks + 1 < nk) STAGE(ks + 1, As[cur ^ 1], Bs[cur ^ 1]);
    short8 af[4], bfr[4];
#pragma unroll
    for (int i = 0; i < 4; ++i) {
      af[i] = *(const short8*)(As[cur] + (wm * 64 + i * 16 + lo) * 32 + (hi ^ rsw) * 8);
      bfr[i] = *(const short8*)(Bs[cur] + (wn * 64 + i * 16 + lo) * 32 + (hi ^ rsw) * 8);
    }
#pragma unroll
    for (int i = 0; i < 4; ++i)
#pragma unroll
      for (int j = 0; j < 4; ++j)
        acc[i][j] = __builtin_amdgcn_mfma_f32_16x16x32_bf16(bfr[j], af[i], acc[i][j], 0, 0, 0);
    __syncthreads();
    cur ^= 1;
  }
#undef STAGE

  gemm_epilogue<EPI>(acc, m0 + wm * 64, n0 + wn * 64, lo, hi, bias, resid, Cout,
                     pq, pk, pv, Nn);
}

// ---------------- attention: 1 wave per (b,h,qt); SWAPPED QK^T.
// s[kt] = mfma(K,Q,bias_c): lane holds P[key=kt*16+hi*4+e][q=lo].
// Softmax: per-lane partial sum + 2 shfl_xor(16,32) full-row reduce; one rcp.
// P relayout: 13 packed ds_write_b64 (4 consecutive keys per lane per kt).
__global__ __launch_bounds__(256) void k_attn(const bf16* __restrict__ Qp,
                                              const bf16* __restrict__ Kp,
                                              const bf16* __restrict__ Vtp,
                                              const f32x4* __restrict__ bias_c,
                                              bf16* __restrict__ out) {
  __shared__ __align__(16) bf16 Ps[4][16][232];
  const int tid = threadIdx.x;
  const int wave = tid >> 6, lane = tid & 63;
  const int lo = lane & 15, hi = lane >> 4;
  const int nwg = gridDim.x;
  const int swz = (blockIdx.x & 7) * (nwg >> 3) + (blockIdx.x >> 3);
  const int unit = swz * 4 + wave;          // 0..39935
  const int bh = unit / 13;
  const int qt = unit - bh * 13;
  const int h = bh % 12;
  const int b = bh / 12;
  const bf16* Qb = Qp + (size_t)bh * BH_STRIDE;
  const bf16* Kb = Kp + (size_t)bh * BH_STRIDE;
  const bf16* Vb = Vtp + (size_t)bh * BH_STRIDE;
  const f32x4* bc = bias_c + ((size_t)(h * 13 + qt) * 13) * 64 + lane;

  // zero this wave's P pad cols 208..223
  for (int i = lane; i < 256; i += 64)
    Ps[wave][i >> 4][208 + (i & 15)] = __float2bfloat16(0.f);

  short8 qf = *(const short8*)(Qb + (qt * 16 + lo) * 32 + hi * 8);

  f32x4 s[13];
  __builtin_amdgcn_s_setprio(1);
#pragma unroll
  for (int kt = 0; kt < 13; ++kt) {
    short8 kf = *(const short8*)(Kb + (kt * 16 + lo) * 32 + hi * 8);
    s[kt] = __builtin_amdgcn_mfma_f32_16x16x32_bf16(kf, qf, bc[kt * 64], 0, 0, 0);
  }
  __builtin_amdgcn_s_setprio(0);

  // p = 2^s; per-lane partial row-sum (q = lo), then reduce over hi groups
  float sm = 0.f;
#pragma unroll
  for (int kt = 0; kt < 13; ++kt) {
#pragma unroll
    for (int e = 0; e < 4; ++e) {
      float pe = __builtin_amdgcn_exp2f(s[kt][e]);
      s[kt][e] = pe;
      sm += pe;
    }
  }
  sm += __shfl_xor(sm, 16);
  sm += __shfl_xor(sm, 32);
  float invq = __builtin_amdgcn_rcpf(sm);   // 1/rowsum for q = lo

  // P -> LDS: packed 4-key writes, row = q = lo
#pragma unroll
  for (int kt = 0; kt < 13; ++kt) {
    union { short4v v; bf16 x[4]; } pack;
#pragma unroll
    for (int e = 0; e < 4; ++e) pack.x[e] = __float2bfloat16(s[kt][e]);
    *(short4v*)(&Ps[wave][lo][kt * 16 + hi * 4]) = pack.v;
  }

  // O = P V (unnormalized P)
  f32x4 o[2] = {{0.f, 0.f, 0.f, 0.f}, {0.f, 0.f, 0.f, 0.f}};
  __builtin_amdgcn_s_setprio(1);
#pragma unroll
  for (int c = 0; c < 7; ++c) {
    short8 pa = *(const short8*)(&Ps[wave][lo][c * 32 + hi * 8]);
#pragma unroll
    for (int n = 0; n < 2; ++n) {
      short8 vf = *(const short8*)(Vb + (n * 16 + lo) * BPAD + c * 32 + hi * 8);
      o[n] = __builtin_amdgcn_mfma_f32_16x16x32_bf16(pa, vf, o[n], 0, 0, 0);
    }
  }
  __builtin_amdgcn_s_setprio(0);

  // output row hi*4+e needs inv of q-row hi*4+e (lives in lane lo = hi*4+e)
  f32x4 inv;
#pragma unroll
  for (int e = 0; e < 4; ++e) inv[e] = __shfl(invq, hi * 4 + e);

#pragma unroll
  for (int n = 0; n < 2; ++n) {
#pragma unroll
    for (int e = 0; e < 4; ++e) {
      int qg = qt * 16 + hi * 4 + e;
      if (qg < NTOK)
        out[(size_t)(b * NTOK + qg) * NDIM + h * HD + n * 16 + lo] =
            __float2bfloat16(o[n][e] * inv[e]);
    }
  }
}

extern "C" void kernel_launch(void* const* d_in, const int* in_sizes, int n_in,
                              void* d_out, int out_size, void* d_ws, size_t ws_size,
                              hipStream_t stream) {
  const float* x       = (const float*)d_in[0];
  const float* norm1_w = (const float*)d_in[1];
  const float* norm1_b = (const float*)d_in[2];
  const float* qkv_w   = (const float*)d_in[3];
  const float* qkv_b   = (const float*)d_in[4];
  const float* proj_w  = (const float*)d_in[5];
  const float* proj_b  = (const float*)d_in[6];
  const float* rpb     = (const float*)d_in[7];
  const float* norm2_w = (const float*)d_in[8];
  const float* norm2_b = (const float*)d_in[9];
  const float* fc1_w   = (const float*)d_in[10];
  const float* fc1_b   = (const float*)d_in[11];
  const float* fc2_w   = (const float*)d_in[12];
  const float* fc2_b   = (const float*)d_in[13];
  const int*   rpi     = (const int*)d_in[14];
  float* out = (float*)d_out;

  char* ws = (char*)d_ws;
  bf16* pad_q = (bf16*)ws;
  bf16* pad_k = (bf16*)(ws + 44040192);
  bf16* pad_v = (bf16*)(ws + 2 * 44040192);
  f32x4* bias_c = (f32x4*)(ws + 3 * 44040192);  // 12*13*13*64*16B = 2,076,672 B
  bf16* mlp1 = (bf16*)ws;
  bf16* hbuf = (bf16*)(ws + 154140672);
  bf16* wqkv_t = (bf16*)(ws + 154140672 + 38535168);
  bf16* wproj_t = wqkv_t + 442368;
  bf16* wfc1_t = wproj_t + 147456;
  bf16* wfc2_t = wfc1_t + 589824;

  k_transpose_bf16<<<(442368 + 255) / 256, 256, 0, stream>>>(qkv_w, wqkv_t, 384, 1152);
  k_transpose_bf16<<<(147456 + 255) / 256, 256, 0, stream>>>(proj_w, wproj_t, 384, 384);
  k_transpose_bf16<<<(589824 + 255) / 256, 256, 0, stream>>>(fc1_w, wfc1_t, 384, 1536);
  k_transpose_bf16<<<(589824 + 255) / 256, 256, 0, stream>>>(fc2_w, wfc2_t, 1536, 384);
  k_build_biasc<<<(NHEADS * 13 * 13 * 64 + 255) / 256, 256, 0, stream>>>(rpb, rpi, bias_c);

  // h1 = LN1(x)
  k_layernorm<<<M_TOK / 4, 256, 0, stream>>>(x, norm1_w, norm1_b, hbuf);
  // qkv = h1 @ qkv_w + qkv_b, scattered into padded per-head buffers
  k_gemm_bt<3><<<196 * 9, 512, 0, stream>>>(hbuf, wqkv_t, qkv_b, nullptr, nullptr,
                                            pad_q, pad_k, pad_v, 1152, 384, 9);
  // attn_out = softmax(q k^T * scale + bias) v
  k_attn<<<9984, 256, 0, stream>>>(pad_q, pad_k, pad_v, bias_c, hbuf);
  // x2 = x + attn_out @ proj_w + proj_b
  k_gemm_bt<2><<<196 * 3, 512, 0, stream>>>(hbuf, wproj_t, proj_b, x, out,
                                            nullptr, nullptr, nullptr, 384, 384, 3);
  // h2 = LN2(x2)
  k_layernorm<<<M_TOK / 4, 256, 0, stream>>>(out, norm2_w, norm2_b, hbuf);
  // mlp1 = gelu(h2 @ fc1_w + fc1_b)
  k_gemm_bt<1><<<196 * 12, 512, 0, stream>>>(hbuf, wfc1_t, fc1_b, nullptr, mlp1,
                                             nullptr, nullptr, nullptr, 1536, 384, 12);
  // out = x2 + mlp1 @ fc2_w + fc2_b
  k_gemm_bt<2><<<196 * 3, 512, 0, stream>>>(mlp1, wfc2_t, fc2_b, out, out,
                                            nullptr, nullptr, nullptr, 384, 1536, 3);
}